// Round 11
// baseline (749.267 us; speedup 1.0000x reference)
//
#include <hip/hip_runtime.h>

#define D_ 768
#define B_ 2048
#define NDOM 9
#define NTOT 10
#define MT 128
#define KT 32
#define KI1 (D_ / KT)   // 24

#define E2   589824ull        // 768*768
#define E2G  1179648ull       // 1536*768
#define OFF_WT2 31850496ull   // 54*E2
#define OFF_SW1 63700992ull   // 108*E2
#define OFF_SW2 66060288ull   // 112*E2
#define OFF_GW1 68419584ull   // 116*E2
#define ZWE     79036416ull   // OFF_GW1 + 9*E2G

typedef _Float16 f16;
typedef _Float16 f16x8 __attribute__((ext_vector_type(8)));
typedef float f32x4 __attribute__((ext_vector_type(4)));

typedef const __attribute__((address_space(1))) void gas_void;
typedef __attribute__((address_space(3))) void las_void;

__device__ __forceinline__ void gload16(const f16* g, f16* l) {
  __builtin_amdgcn_global_load_lds((gas_void*)g, (las_void*)l, 16, 0, 0);
}

// ---------------------------------------------------------------- bucket ----
__global__ __launch_bounds__(256) void bucket_kernel(const int* cat32, int* perm,
                                                     int* off, int* cnt, int* dom) {
  __shared__ int scnt[NDOM], soff[NDOM], scur[NDOM];
  __shared__ int odd_nz;
  int t = threadIdx.x;
  if (t == 0) odd_nz = 0;
  if (t < NDOM) scnt[t] = 0;
  __syncthreads();
  int loc = 0;
  for (int i = t; i < B_; i += 256)
    if ((i & 1) && cat32[i] != 0) loc = 1;
  if (loc) atomicOr(&odd_nz, 1);
  __syncthreads();
  int strd = odd_nz ? 1 : 2;
  for (int i = t; i < B_; i += 256) atomicAdd(&scnt[cat32[i * strd]], 1);
  __syncthreads();
  if (t == 0) { int a = 0; for (int n = 0; n < NDOM; n++) { soff[n] = a; a += scnt[n]; } }
  __syncthreads();
  if (t < NDOM) { scur[t] = soff[t]; off[t] = soff[t]; cnt[t] = scnt[t]; }
  __syncthreads();
  for (int i = t; i < B_; i += 256) {
    int n = cat32[i * strd];
    int pos = atomicAdd(&scur[n], 1);
    perm[pos] = i;
    dom[pos] = n;
  }
}

// ------------------------------------------------------------ cvt+permute ---
__global__ __launch_bounds__(256) void cvt_perm_kernel(const float* src, f16* dst,
                                                       const int* perm, int n8) {
  int i = blockIdx.x * 256 + threadIdx.x;
  if (i >= n8) return;
  int row = i / (D_ / 8), c8 = i % (D_ / 8);
  int srow = perm[row];
  const f32x4* s = (const f32x4*)(src + (size_t)srow * D_ + c8 * 8);
  f32x4 a = s[0], b = s[1];
  f16x8 o;
  o[0]=(f16)a[0]; o[1]=(f16)a[1]; o[2]=(f16)a[2]; o[3]=(f16)a[3];
  o[4]=(f16)b[0]; o[5]=(f16)b[1]; o[6]=(f16)b[2]; o[7]=(f16)b[3];
  *(f16x8*)(dst + (size_t)i * 8) = o;
}

// ------------------------------------------------------------ gate demb -----
struct DGP { const float* demb; const float* gW1[2]; const float* gb1[2]; float* dg; };

__global__ __launch_bounds__(256) void dgate_kernel(DGP p) {
  const int jc = blockIdx.x, n = blockIdx.y, z = blockIdx.z;
  const int j = jc * 256 + threadIdx.x;
  const float* W = p.gW1[z] + (size_t)n * 2 * D_ * D_;
  const float* de = p.demb + (size_t)n * D_;
  float acc = 0.f;
  for (int k = 0; k < D_; k++) acc = fmaf(de[k], W[(size_t)k * D_ + j], acc);
  p.dg[((size_t)z * NDOM + n) * D_ + j] = acc + p.gb1[z][n * D_ + j];
}

// ------------------------------------------------------------ transpose -----
struct TRP { const float* s[10]; f16* wt; };

__global__ __launch_bounds__(256) void trans_kernel(TRP p) {
  const int m = blockIdx.z, z = m / 125, r = m % 125;
  const float* src; f16* dst; int R;
  const size_t zw = (size_t)z * ZWE;
  if (r < 54)       { src = p.s[0+z] + (size_t)r*E2;        dst = p.wt + zw + (size_t)r*E2;                 R = 768; }
  else if (r < 108) { int i=r-54;  src = p.s[2+z] + (size_t)i*E2;  dst = p.wt + zw + OFF_WT2 + (size_t)i*E2;  R = 768; }
  else if (r < 112) { int i=r-108; src = p.s[4+z] + (size_t)i*E2;  dst = p.wt + zw + OFF_SW1 + (size_t)i*E2;  R = 768; }
  else if (r < 116) { int i=r-112; src = p.s[6+z] + (size_t)i*E2;  dst = p.wt + zw + OFF_SW2 + (size_t)i*E2;  R = 768; }
  else              { int i=r-116; src = p.s[8+z] + (size_t)i*E2G; dst = p.wt + zw + OFF_GW1 + (size_t)i*E2G; R = 1536; }
  const int ty = blockIdx.y;
  if (ty * 64 >= R) return;
  if (R == 1536 && ty < 12) return;   // demb-half of gW1 hoisted into dgate
  const int tx = blockIdx.x;

  __shared__ float tile[64][65];
  const int t = threadIdx.x;
  const int lr = t >> 4, lc = (t & 15) * 4;
#pragma unroll
  for (int i = 0; i < 4; i++) {
    int row = lr + i * 16;
    f32x4 v = *(const f32x4*)(src + (size_t)(ty*64 + row) * 768 + tx*64 + lc);
    tile[lc+0][row] = v[0];
    tile[lc+1][row] = v[1];
    tile[lc+2][row] = v[2];
    tile[lc+3][row] = v[3];
  }
  __syncthreads();
  const int orow = t >> 3, oc = (t & 7) * 8;
#pragma unroll
  for (int i = 0; i < 2; i++) {
    int r2 = orow + i * 32;
    f32x4 a = *(const f32x4*)&tile[r2][oc];
    f32x4 b = *(const f32x4*)&tile[r2][oc + 4];
    f16x8 o;
    o[0]=(f16)a[0]; o[1]=(f16)a[1]; o[2]=(f16)a[2]; o[3]=(f16)a[3];
    o[4]=(f16)b[0]; o[5]=(f16)b[1]; o[6]=(f16)b[2]; o[7]=(f16)b[3];
    *(f16x8*)(dst + (size_t)(tx*64 + r2) * R + ty*64 + oc) = o;
  }
}

// ---------------------------------------------------------------- layer 1 ---
struct L1P {
  const f16* x16p[2]; const f16* wt;
  const float* b1[2]; const float* sb1[2]; const float* dg;
  const int* off; const int* cnt;
  f16* h;
};

#define NBL1 3792
#define QX1  474

__global__ __launch_bounds__(256, 4) void layer1_kernel(L1P p) {
  const int raw = blockIdx.x;
  const int L = (raw & 7) * QX1 + (raw >> 3);
  const int z = L / 1896;
  const int rem = L - z * 1896;
  const int g = rem / 24;
  const int x = rem % 24;
  const int nt = x % 6;
  int mt0 = x / 6, mtstep = 4;

  int row_off, row_cnt, slot;
  const f16* WT; const float* bias;
  int KW = D_, koff = 0;
  const size_t zw = (size_t)z * ZWE;
  if (g < 54) {
    int n = g / 6, e = g % 6;
    row_off = p.off[n]; row_cnt = p.cnt[n];
    WT = p.wt + zw + (size_t)(n*6+e) * E2;
    bias = p.b1[z] + (n*6+e) * D_;
    slot = e;
  } else if (g < 70) {
    int s_ = g - 54, e = s_ >> 2;
    row_off = 0; row_cnt = B_;
    WT = p.wt + zw + OFF_SW1 + (size_t)e * E2;
    bias = p.sb1[z] + e * D_;
    slot = 6 + e;
    mt0 = x / 6 + 4 * (s_ & 3); mtstep = 16;
  } else {
    int n = g - 70;
    row_off = p.off[n]; row_cnt = p.cnt[n];
    WT = p.wt + zw + OFF_GW1 + (size_t)n * E2G;
    bias = p.dg + (size_t)(z * NDOM + n) * D_;
    slot = 10; KW = 2 * D_; koff = D_;
  }
  if (mt0 * MT >= row_cnt) return;

  __shared__ f16 smem[16384];   // 32 KB: As[2]|Bs[2] during K-loop; flat 128x128 in epilogue
  f16 (*As)[MT][KT] = (f16(*)[MT][KT])smem;
  f16 (*Bs)[MT][KT] = (f16(*)[MT][KT])(smem + 8192);
  f16* Ts = smem;

  const int t = threadIdx.x;
  const int wave = t >> 6, lane = t & 63;
  const int wr = (wave >> 1) * 64, wc = (wave & 1) * 64;
  const int r0 = lane & 15, q = lane >> 4;
  const int lrow = lane >> 2;
  const int lk = 8 * ((lane & 3) ^ ((lane >> 3) & 3));
  const int qa = (q ^ ((r0 >> 1) & 3)) * 8;
  const int jbase = nt * MT;

  const f16* bBase[2];
#pragma unroll
  for (int i = 0; i < 2; i++) {
    int col = jbase + 32 * wave + 16 * i + lrow;
    bBase[i] = WT + (size_t)col * KW + koff + lk;
  }
  const f16* xz = p.x16p[z];

  for (int mt = mt0; mt * MT < row_cnt; mt += mtstep) {
    const f16* aBase[2];
#pragma unroll
    for (int i = 0; i < 2; i++) {
      int rl = mt * MT + 32 * wave + 16 * i + lrow;
      if (rl >= row_cnt) rl = row_cnt - 1;
      aBase[i] = xz + (size_t)(row_off + rl) * D_ + lk;
    }

    auto STAGE = [&](int buf, int kk) {
      const int k0 = kk * KT;
      gload16(aBase[0] + k0, &As[buf][32 * wave][0]);
      gload16(aBase[1] + k0, &As[buf][32 * wave + 16][0]);
      gload16(bBase[0] + k0, &Bs[buf][32 * wave][0]);
      gload16(bBase[1] + k0, &Bs[buf][32 * wave + 16][0]);
    };

    f32x4 acc[4][4];
#pragma unroll
    for (int a = 0; a < 4; a++)
#pragma unroll
      for (int b = 0; b < 4; b++) acc[a][b] = (f32x4){0.f, 0.f, 0.f, 0.f};

    STAGE(0, 0);
    __syncthreads();
    for (int kk = 0; kk < KI1; kk++) {
      const int cur = kk & 1;
      if (kk + 1 < KI1) STAGE(cur ^ 1, kk + 1);
      f16x8 af[4], bf[4];
#pragma unroll
      for (int m = 0; m < 4; m++) af[m] = *(const f16x8*)&As[cur][wr + m * 16 + r0][qa];
#pragma unroll
      for (int nn = 0; nn < 4; nn++) bf[nn] = *(const f16x8*)&Bs[cur][wc + nn * 16 + r0][qa];
#pragma unroll
      for (int m = 0; m < 4; m++)
#pragma unroll
        for (int nn = 0; nn < 4; nn++)
          acc[m][nn] = __builtin_amdgcn_mfma_f32_16x16x32_f16(af[m], bf[nn], acc[m][nn], 0, 0, 0);
      __syncthreads();
    }

    // --- epilogue: bias+SiLU, LDS transpose (chunk-XOR), wide coalesced stores
#pragma unroll
    for (int nn = 0; nn < 4; nn++) {
      const int col = wc + nn * 16 + r0;          // tile-local col
      const float bc = bias[jbase + col];
#pragma unroll
      for (int m = 0; m < 4; m++) {
#pragma unroll
        for (int i = 0; i < 4; i++) {
          int row = wr + m * 16 + q * 4 + i;      // tile-local row
          float v = acc[m][nn][i] + bc;
          v = v / (1.f + __expf(-v));
          int ch = (col >> 3) ^ (row & 7);
          Ts[row * 128 + ch * 8 + (col & 7)] = (f16)v;
        }
      }
    }
    __syncthreads();
    {
      f16* hout = p.h + (size_t)(z * 11 + slot) * B_ * D_;
      int row = t >> 1;
      int gr = mt * MT + row;
      if (gr < row_cnt) {
        f16* dst = hout + (size_t)(row_off + gr) * D_ + jbase + (t & 1) * 64;
#pragma unroll
        for (int c8 = 0; c8 < 8; c8++) {
          int ch = (((t & 1) * 8 + c8)) ^ (row & 7);
          *(f16x8*)(dst + c8 * 8) = *(const f16x8*)&Ts[row * 128 + ch * 8];
        }
      }
    }
    __syncthreads();   // smem reused by next mt STAGE
  }
}

// ---------------------------------------------------------------- gate ------
struct GP {
  const f16* h;
  const float* gW2[2]; const float* gb2[2]; const float* temp[2];
  const int* dom;
  float* gates;
};

__global__ __launch_bounds__(256) void gate_kernel(GP p) {
  int wid = (blockIdx.x * 256 + threadIdx.x) >> 6;
  int lane = threadIdx.x & 63;
  int z = wid >> 11;
  int pos = wid & (B_ - 1);
  int n = p.dom[pos];
  const f16* gh = p.h + ((size_t)(z * 11 + 10) * B_ + pos) * D_;
  const float* W = p.gW2[z] + (size_t)n * D_ * NTOT;
  float part[NTOT];
#pragma unroll
  for (int e = 0; e < NTOT; e++) part[e] = 0.f;
  for (int k = lane; k < D_; k += 64) {
    float a = (float)gh[k];
    const float* wrow = W + (size_t)k * NTOT;
#pragma unroll
    for (int e = 0; e < NTOT; e++) part[e] = fmaf(a, wrow[e], part[e]);
  }
#pragma unroll
  for (int e = 0; e < NTOT; e++) {
    float v = part[e];
#pragma unroll
    for (int s = 32; s > 0; s >>= 1) v += __shfl_xor(v, s, 64);
    part[e] = v;
  }
  float tv = p.temp[z][n];
  float tq = (tv > 15.f ? tv : log1pf(__expf(tv))) + 1e-4f;
  const float* b2 = p.gb2[z] + n * NTOT;
  float mx = -1e30f;
#pragma unroll
  for (int e = 0; e < NTOT; e++) { part[e] = (part[e] + b2[e]) / tq; mx = fmaxf(mx, part[e]); }
  float s = 0.f;
#pragma unroll
  for (int e = 0; e < NTOT; e++) { part[e] = __expf(part[e] - mx); s += part[e]; }
  float inv = 1.f / s;
  if (lane < NTOT) p.gates[((size_t)z * B_ + pos) * NTOT + lane] = part[lane] * inv;
}

// ---------------------------------------------------------------- layer 2 ---
// Plain f16 slice-buffer stores (no atomics); reduce kernel sums 5 slices.
struct L2P {
  const f16* h; const f16* wt;
  const float* b2[2]; const float* sb2[2];
  const float* gates;
  const int* off; const int* cnt;
  f16* outp;   // [10][B_][768]
};

#define NBL2 2160
#define QX2  270

__global__ __launch_bounds__(256, 4) void layer2_kernel(L2P p) {
  const int raw = blockIdx.x;
  const int L = (raw & 7) * QX2 + (raw >> 3);
  const int zz = L / 216;
  const int rem = L % 216;
  const int n = rem / 24;
  const int x = rem % 24;
  const int z = zz / 5, es = zz % 5, ebase = es * 2;
  const int nt = x % 6, mt0 = x / 6;
  const int row_off = p.off[n], row_cnt = p.cnt[n];
  if (mt0 * MT >= row_cnt) return;

  __shared__ f16 smem[16384];
  f16 (*As)[MT][KT] = (f16(*)[MT][KT])smem;
  f16 (*Bs)[MT][KT] = (f16(*)[MT][KT])(smem + 8192);
  f16* Ts = smem;
  __shared__ float sg[MT][2];

  const int t = threadIdx.x;
  const int wave = t >> 6, lane = t & 63;
  const int wr = (wave >> 1) * 64, wc = (wave & 1) * 64;
  const int r0 = lane & 15, q = lane >> 4;
  const int lrow = lane >> 2;
  const int lk = 8 * ((lane & 3) ^ ((lane >> 3) & 3));
  const int qa = (q ^ ((r0 >> 1) & 3)) * 8;
  const int jbase = nt * MT;

  const size_t zw = (size_t)z * ZWE;
  const f16* WB0; const f16* WB1; const float* pb[2]; size_t slotOff[2];
  {
    int e0 = ebase, e1 = ebase + 1;
    WB0 = (e0 < 6) ? (p.wt + zw + OFF_WT2 + (size_t)(n*6+e0)*E2) : (p.wt + zw + OFF_SW2 + (size_t)(e0-6)*E2);
    WB1 = (e1 < 6) ? (p.wt + zw + OFF_WT2 + (size_t)(n*6+e1)*E2) : (p.wt + zw + OFF_SW2 + (size_t)(e1-6)*E2);
    pb[0] = (e0 < 6) ? (p.b2[z] + (size_t)(n*6+e0)*D_) : (p.sb2[z] + (size_t)(e0-6)*D_);
    pb[1] = (e1 < 6) ? (p.b2[z] + (size_t)(n*6+e1)*D_) : (p.sb2[z] + (size_t)(e1-6)*D_);
    slotOff[0] = (size_t)(z*11 + e0) * B_ * D_;
    slotOff[1] = (size_t)(z*11 + e1) * B_ * D_;
  }

  const f16* bB0[2]; const f16* bB1[2];
#pragma unroll
  for (int i = 0; i < 2; i++) {
    int col = jbase + 32 * wave + 16 * i + lrow;
    bB0[i] = WB0 + (size_t)col * D_ + lk;
    bB1[i] = WB1 + (size_t)col * D_ + lk;
  }

  for (int mt = mt0; mt * MT < row_cnt; mt += 4) {
    for (int i = t; i < MT * 2; i += 256) {
      int rr = i >> 1, e = i & 1;
      int gp = row_off + mt * MT + rr;
      sg[rr][e] = (gp < B_ && (mt * MT + rr) < row_cnt)
                  ? p.gates[((size_t)z * B_ + gp) * NTOT + ebase + e] : 0.f;
    }
    __syncthreads();

    const f16* aB0[2]; const f16* aB1[2];
#pragma unroll
    for (int i = 0; i < 2; i++) {
      int rl = mt * MT + 32 * wave + 16 * i + lrow;
      int rr = (rl < row_cnt) ? (row_off + rl) : row_off;
      size_t rp = (size_t)rr * D_ + lk;
      aB0[i] = p.h + slotOff[0] + rp;
      aB1[i] = p.h + slotOff[1] + rp;
    }
    f16 gA[4], gB[4];
#pragma unroll
    for (int m = 0; m < 4; m++) {
      gA[m] = (f16)sg[wr + m * 16 + r0][0];
      gB[m] = (f16)sg[wr + m * 16 + r0][1];
    }

    auto STAGE = [&](int buf, int it) {
      const int ei = (it >= KI1);
      const int k0 = (it - (ei ? KI1 : 0)) * KT;
      gload16((ei ? aB1[0] : aB0[0]) + k0, &As[buf][32 * wave][0]);
      gload16((ei ? aB1[1] : aB0[1]) + k0, &As[buf][32 * wave + 16][0]);
      gload16((ei ? bB1[0] : bB0[0]) + k0, &Bs[buf][32 * wave][0]);
      gload16((ei ? bB1[1] : bB0[1]) + k0, &Bs[buf][32 * wave + 16][0]);
    };

    f32x4 acc[4][4];
#pragma unroll
    for (int a = 0; a < 4; a++)
#pragma unroll
      for (int b = 0; b < 4; b++) acc[a][b] = (f32x4){0.f, 0.f, 0.f, 0.f};

    const int total = 2 * KI1;
    STAGE(0, 0);
    __syncthreads();
    for (int it = 0; it < total; it++) {
      const int cur = it & 1;
      if (it + 1 < total) STAGE(cur ^ 1, it + 1);
      const int ei = (it >= KI1);
      f16x8 af[4], bf[4];
#pragma unroll
      for (int m = 0; m < 4; m++) {
        af[m] = *(const f16x8*)&As[cur][wr + m * 16 + r0][qa];
        af[m] = af[m] * (ei ? gB[m] : gA[m]);
      }
#pragma unroll
      for (int nn = 0; nn < 4; nn++) bf[nn] = *(const f16x8*)&Bs[cur][wc + nn * 16 + r0][qa];
#pragma unroll
      for (int m = 0; m < 4; m++)
#pragma unroll
        for (int nn = 0; nn < 4; nn++)
          acc[m][nn] = __builtin_amdgcn_mfma_f32_16x16x32_f16(af[m], bf[nn], acc[m][nn], 0, 0, 0);
      __syncthreads();
    }

    // --- epilogue: gate-bias add, LDS transpose, plain wide f16 stores
#pragma unroll
    for (int nn = 0; nn < 4; nn++) {
      const int col = wc + nn * 16 + r0;
      const float pbc0 = pb[0][jbase + col], pbc1 = pb[1][jbase + col];
#pragma unroll
      for (int m = 0; m < 4; m++) {
#pragma unroll
        for (int i = 0; i < 4; i++) {
          int row = wr + m * 16 + q * 4 + i;
          float v = acc[m][nn][i];
          v = fmaf(sg[row][0], pbc0, v);
          v = fmaf(sg[row][1], pbc1, v);
          int ch = (col >> 3) ^ (row & 7);
          Ts[row * 128 + ch * 8 + (col & 7)] = (f16)v;
        }
      }
    }
    __syncthreads();
    {
      int row = t >> 1;
      int gr = mt * MT + row;
      if (gr < row_cnt) {
        f16* dst = p.outp + ((size_t)zz * B_ + row_off + gr) * D_ + jbase + (t & 1) * 64;
#pragma unroll
        for (int c8 = 0; c8 < 8; c8++) {
          int ch = (((t & 1) * 8 + c8)) ^ (row & 7);
          *(f16x8*)(dst + c8 * 8) = *(const f16x8*)&Ts[row * 128 + ch * 8];
        }
      }
    }
    __syncthreads();
  }
}

// ---------------------------------------------------------------- reduce ----
__global__ __launch_bounds__(256) void reduce_kernel(const f16* outp, const int* perm,
                                                     float* out) {
  int idx = blockIdx.x * 256 + threadIdx.x;   // 2 * B_ * 96 total
  int z = idx / (B_ * 96);
  int rem = idx % (B_ * 96);
  int r = rem / 96, c8 = rem % 96;
  float s[8];
#pragma unroll
  for (int j = 0; j < 8; j++) s[j] = 0.f;
#pragma unroll
  for (int es = 0; es < 5; es++) {
    f16x8 v = *(const f16x8*)(outp + (((size_t)(z * 5 + es)) * B_ + r) * D_ + c8 * 8);
#pragma unroll
    for (int j = 0; j < 8; j++) s[j] += (float)v[j];
  }
  float* dst = out + (size_t)perm[r] * (2 * D_) + z * D_ + c8 * 8;
  *(f32x4*)dst = (f32x4){s[0], s[1], s[2], s[3]};
  *(f32x4*)(dst + 4) = (f32x4){s[4], s[5], s[6], s[7]};
}

// ---------------------------------------------------------------- launch ----
extern "C" void kernel_launch(void* const* d_in, const int* in_sizes, int n_in,
                              void* d_out, int out_size, void* d_ws, size_t ws_size,
                              hipStream_t stream) {
  const float* content = (const float*)d_in[0];
  const float* ftr     = (const float*)d_in[1];
  const int*   cat     = (const int*)d_in[2];
  const float* demb    = (const float*)d_in[3];

  const float* cW1  = (const float*)d_in[4];
  const float* cb1  = (const float*)d_in[5];
  const float* cW2  = (const float*)d_in[6];
  const float* cb2  = (const float*)d_in[7];
  const float* csW1 = (const float*)d_in[8];
  const float* csb1 = (const float*)d_in[9];
  const float* csW2 = (const float*)d_in[10];
  const float* csb2 = (const float*)d_in[11];
  const float* cgW1 = (const float*)d_in[12];
  const float* cgb1 = (const float*)d_in[13];
  const float* cgW2 = (const float*)d_in[14];
  const float* cgb2 = (const float*)d_in[15];
  const float* ctemp= (const float*)d_in[16];

  const float* fW1  = (const float*)d_in[17];
  const float* fb1  = (const float*)d_in[18];
  const float* fW2  = (const float*)d_in[19];
  const float* fb2  = (const float*)d_in[20];
  const float* fsW1 = (const float*)d_in[21];
  const float* fsb1 = (const float*)d_in[22];
  const float* fsW2 = (const float*)d_in[23];
  const float* fsb2 = (const float*)d_in[24];
  const float* fgW1 = (const float*)d_in[25];
  const float* fgb1 = (const float*)d_in[26];
  const float* fgW2 = (const float*)d_in[27];
  const float* fgb2 = (const float*)d_in[28];
  const float* ftemp= (const float*)d_in[29];

  char* wsb = (char*)d_ws;
  int* perm    = (int*)wsb;
  int* off     = (int*)(wsb + 8192);
  int* cnt     = (int*)(wsb + 8256);
  int* dom     = (int*)(wsb + 8320);
  float* gates = (float*)(wsb + 16512);
  float* dg    = (float*)(wsb + 16512 + 163840);   // 55 KB (disjoint from gates)
  f16* h       = (f16*)(wsb + 409600);             // 66 MB
  f16* x16a    = (f16*)(wsb + 69615616);           // 3 MB
  f16* x16b    = (f16*)(wsb + 72761344);           // 3 MB
  f16* wt      = (f16*)(wsb + 75907072);           // 316 MB
  f16* outp    = wt;                               // aliases dead W1 region (layer2 reads >= OFF_WT2)
  float* out   = (float*)d_out;

  bucket_kernel<<<1, 256, 0, stream>>>(cat, perm, off, cnt, dom);

  cvt_perm_kernel<<<768, 256, 0, stream>>>(content, x16a, perm, (B_ * D_) / 8);
  cvt_perm_kernel<<<768, 256, 0, stream>>>(ftr, x16b, perm, (B_ * D_) / 8);

  DGP pd;
  pd.demb = demb; pd.gW1[0] = cgW1; pd.gW1[1] = fgW1;
  pd.gb1[0] = cgb1; pd.gb1[1] = fgb1; pd.dg = dg;
  dgate_kernel<<<dim3(3, 9, 2), 256, 0, stream>>>(pd);

  TRP tp;
  tp.s[0] = cW1;  tp.s[1] = fW1;
  tp.s[2] = cW2;  tp.s[3] = fW2;
  tp.s[4] = csW1; tp.s[5] = fsW1;
  tp.s[6] = csW2; tp.s[7] = fsW2;
  tp.s[8] = cgW1; tp.s[9] = fgW1;
  tp.wt = wt;
  trans_kernel<<<dim3(12, 24, 250), 256, 0, stream>>>(tp);

  L1P p1;
  p1.x16p[0] = x16a; p1.x16p[1] = x16b; p1.wt = wt;
  p1.b1[0] = cb1;  p1.b1[1] = fb1;
  p1.sb1[0] = csb1; p1.sb1[1] = fsb1;
  p1.dg = dg;
  p1.off = off; p1.cnt = cnt; p1.h = h;
  layer1_kernel<<<dim3(NBL1), 256, 0, stream>>>(p1);

  GP pg;
  pg.h = h; pg.gW2[0] = cgW2; pg.gW2[1] = fgW2;
  pg.gb2[0] = cgb2; pg.gb2[1] = fgb2;
  pg.temp[0] = ctemp; pg.temp[1] = ftemp;
  pg.dom = dom; pg.gates = gates;
  gate_kernel<<<dim3((2 * B_) / 4), 256, 0, stream>>>(pg);

  L2P p2;
  p2.h = h; p2.wt = wt;
  p2.b2[0] = cb2;  p2.b2[1] = fb2;
  p2.sb2[0] = csb2; p2.sb2[1] = fsb2;
  p2.gates = gates; p2.off = off; p2.cnt = cnt; p2.outp = outp;
  layer2_kernel<<<dim3(NBL2), 256, 0, stream>>>(p2);

  reduce_kernel<<<dim3((2 * B_ * 96) / 256), 256, 0, stream>>>(outp, perm, out);

  (void)in_sizes; (void)n_in; (void)ws_size; (void)out_size;
}

// Round 12
// 664.262 us; speedup vs baseline: 1.1280x; 1.1280x over previous
//
#include <hip/hip_runtime.h>

#define D_ 768
#define B_ 2048
#define NDOM 9
#define NTOT 10
#define MT 128
#define KT 32
#define KI1 (D_ / KT)   // 24
#define E2 589824ull    // 768*768
#define LDB 40          // padded Bs leading dim (f16): 80 B row, 16B-multiple

typedef _Float16 f16;
typedef _Float16 f16x8 __attribute__((ext_vector_type(8)));
typedef _Float16 f16x4 __attribute__((ext_vector_type(4)));
typedef _Float16 f16x2 __attribute__((ext_vector_type(2)));
typedef float f32x4 __attribute__((ext_vector_type(4)));

typedef const __attribute__((address_space(1))) void gas_void;
typedef __attribute__((address_space(3))) void las_void;

__device__ __forceinline__ void gload16(const f16* g, f16* l) {
  __builtin_amdgcn_global_load_lds((gas_void*)g, (las_void*)l, 16, 0, 0);
}
static __device__ __forceinline__ f16x2 pkrtz(float a, float b) {
  return __builtin_bit_cast(f16x2, __builtin_amdgcn_cvt_pkrtz(a, b));
}
#define SCHED0() __builtin_amdgcn_sched_barrier(0)

// ---------------------------------------------------------------- bucket ----
__global__ __launch_bounds__(256) void bucket_kernel(const int* cat32, int* perm,
                                                     int* off, int* cnt, int* dom) {
  __shared__ int scnt[NDOM], soff[NDOM], scur[NDOM];
  __shared__ int odd_nz;
  int t = threadIdx.x;
  if (t == 0) odd_nz = 0;
  if (t < NDOM) scnt[t] = 0;
  __syncthreads();
  int loc = 0;
  for (int i = t; i < B_; i += 256)
    if ((i & 1) && cat32[i] != 0) loc = 1;
  if (loc) atomicOr(&odd_nz, 1);
  __syncthreads();
  int strd = odd_nz ? 1 : 2;
  for (int i = t; i < B_; i += 256) atomicAdd(&scnt[cat32[i * strd]], 1);
  __syncthreads();
  if (t == 0) { int a = 0; for (int n = 0; n < NDOM; n++) { soff[n] = a; a += scnt[n]; } }
  __syncthreads();
  if (t < NDOM) { scur[t] = soff[t]; off[t] = soff[t]; cnt[t] = scnt[t]; }
  __syncthreads();
  for (int i = t; i < B_; i += 256) {
    int n = cat32[i * strd];
    int pos = atomicAdd(&scur[n], 1);
    perm[pos] = i;
    dom[pos] = n;
  }
}

// ------------------------------------------------------------ cvt+permute ---
__global__ __launch_bounds__(256) void cvt_perm_kernel(const float* src, f16* dst,
                                                       const int* perm, int n8) {
  int i = blockIdx.x * 256 + threadIdx.x;
  if (i >= n8) return;
  int row = i / (D_ / 8), c8 = i % (D_ / 8);
  int srow = perm[row];
  const f32x4* s = (const f32x4*)(src + (size_t)srow * D_ + c8 * 8);
  f32x4 a = s[0], b = s[1];
  f16x8 o;
  o[0]=(f16)a[0]; o[1]=(f16)a[1]; o[2]=(f16)a[2]; o[3]=(f16)a[3];
  o[4]=(f16)b[0]; o[5]=(f16)b[1]; o[6]=(f16)b[2]; o[7]=(f16)b[3];
  *(f16x8*)(dst + (size_t)i * 8) = o;
}

// ------------------------------------------------------------ gate demb -----
struct DGP { const float* demb; const float* gW1[2]; const float* gb1[2]; float* dg; };

__global__ __launch_bounds__(256) void dgate_kernel(DGP p) {
  const int jc = blockIdx.x, n = blockIdx.y, z = blockIdx.z;
  const int j = jc * 256 + threadIdx.x;
  const float* W = p.gW1[z] + (size_t)n * 2 * D_ * D_;
  const float* de = p.demb + (size_t)n * D_;
  float acc = 0.f;
  for (int k = 0; k < D_; k++) acc = fmaf(de[k], W[(size_t)k * D_ + j], acc);
  p.dg[((size_t)z * NDOM + n) * D_ + j] = acc + p.gb1[z][n * D_ + j];
}

// ---------------------------------------------------------------- layer 1 ---
// fp32 weights consumed directly: B reg-staged (f32x4 -> cvt -> padded LDS),
// A via global_load_lds (f16). 128x128 tile, 4 waves, 2-buffer, plain barriers.
struct L1P {
  const f16* x16p[2];
  const float* W1[2]; const float* sW1[2]; const float* gW1[2];
  const float* b1[2]; const float* sb1[2]; const float* dg;
  const int* off; const int* cnt;
  f16* h;
};

#define NBL1 3792
#define QX1  474

__global__ __launch_bounds__(256, 4) void layer1_kernel(L1P p) {
  const int raw = blockIdx.x;
  const int L = (raw & 7) * QX1 + (raw >> 3);   // bijective XCD chunking
  const int z = L / 1896;
  const int rem = L - z * 1896;
  const int g = rem / 24;
  const int x = rem % 24;
  const int nt = x % 6;
  int mt0 = x / 6, mtstep = 4;

  int row_off, row_cnt, slot, koff = 0;
  const float* Wp; const float* bias;
  if (g < 54) {
    int n = g / 6, e = g % 6;
    row_off = p.off[n]; row_cnt = p.cnt[n];
    Wp = p.W1[z] + (size_t)(n*6+e) * E2;
    bias = p.b1[z] + (n*6+e) * D_;
    slot = e;
  } else if (g < 70) {
    int s_ = g - 54, e = s_ >> 2;
    row_off = 0; row_cnt = B_;
    Wp = p.sW1[z] + (size_t)e * E2;
    bias = p.sb1[z] + e * D_;
    slot = 6 + e;
    mt0 = x / 6 + 4 * (s_ & 3); mtstep = 16;
  } else {
    int n = g - 70;
    row_off = p.off[n]; row_cnt = p.cnt[n];
    Wp = p.gW1[z] + (size_t)n * 2 * D_ * D_;
    bias = p.dg + (size_t)(z * NDOM + n) * D_;
    slot = 10; koff = D_;
  }
  if (mt0 * MT >= row_cnt) return;

  __shared__ f16 As[2][MT][KT];    // 16 KB
  __shared__ f16 Bs[2][MT][LDB];   // 20 KB

  const int t = threadIdx.x;
  const int wave = t >> 6, lane = t & 63;
  const int wr = (wave >> 1) * 64, wc = (wave & 1) * 64;
  const int r0 = lane & 15, q = lane >> 4;
  const int lrow = lane >> 2;
  const int lk = 8 * ((lane & 3) ^ ((lane >> 3) & 3));   // A gload source pre-swizzle
  const int qa = (q ^ ((r0 >> 1) & 3)) * 8;              // A frag read swizzle
  const int jbase = nt * MT;
  const int j4 = t >> 3;           // 0..31 -> col group of 4
  const int kq = (t & 7) * 4;      // 0..28 -> k group of 4

  const float* wcol = Wp + jbase + j4 * 4;
  const f16* xz = p.x16p[z];

  for (int mt = mt0; mt * MT < row_cnt; mt += mtstep) {
    const f16* aBase[2];
#pragma unroll
    for (int i = 0; i < 2; i++) {
      int rl = mt * MT + 32 * wave + 16 * i + lrow;
      if (rl >= row_cnt) rl = row_cnt - 1;
      aBase[i] = xz + (size_t)(row_off + rl) * D_ + lk;
    }

    f32x4 wv[4];
    auto LOADW = [&](int kk) {
      const int kb = koff + kk * KT + kq;
#pragma unroll
      for (int r = 0; r < 4; r++) wv[r] = *(const f32x4*)(wcol + (size_t)(kb + r) * D_);
    };
    auto GLOADA = [&](int buf, int kk) {
      const int k0 = kk * KT;
      gload16(aBase[0] + k0, &As[buf][32 * wave][0]);
      gload16(aBase[1] + k0, &As[buf][32 * wave + 16][0]);
    };
    auto CVTW = [&](int buf) {
#pragma unroll
      for (int c = 0; c < 4; c++) {
        union { f16x4 v; f16x2 pp[2]; } u;
        u.pp[0] = pkrtz(wv[0][c], wv[1][c]);
        u.pp[1] = pkrtz(wv[2][c], wv[3][c]);
        *(f16x4*)&Bs[buf][j4 * 4 + c][kq] = u.v;
      }
    };

    f32x4 acc[4][4];
#pragma unroll
    for (int a = 0; a < 4; a++)
#pragma unroll
      for (int b = 0; b < 4; b++) acc[a][b] = (f32x4){0.f, 0.f, 0.f, 0.f};

    LOADW(0);
    GLOADA(0, 0);
    CVTW(0);
    __syncthreads();

    for (int kk = 0; kk < KI1; kk++) {
      const int cur = kk & 1;
      if (kk + 1 < KI1) { LOADW(kk + 1); GLOADA(cur ^ 1, kk + 1); }
      SCHED0();
      f16x8 af[4], bf[4];
#pragma unroll
      for (int m = 0; m < 4; m++) af[m] = *(const f16x8*)&As[cur][wr + m * 16 + r0][qa];
#pragma unroll
      for (int nn = 0; nn < 4; nn++) bf[nn] = *(const f16x8*)&Bs[cur][wc + nn * 16 + r0][q * 8];
#pragma unroll
      for (int m = 0; m < 4; m++)
#pragma unroll
        for (int nn = 0; nn < 4; nn++)
          acc[m][nn] = __builtin_amdgcn_mfma_f32_16x16x32_f16(af[m], bf[nn], acc[m][nn], 0, 0, 0);
      SCHED0();
      if (kk + 1 < KI1) CVTW(cur ^ 1);
      __syncthreads();
    }

    f16* hout = p.h + (size_t)(z * 11 + slot) * B_ * D_;
#pragma unroll
    for (int nn = 0; nn < 4; nn++) {
      const int col = jbase + wc + nn * 16 + r0;
      const float bc = bias[col];
#pragma unroll
      for (int m = 0; m < 4; m++) {
#pragma unroll
        for (int i = 0; i < 4; i++) {
          int lr = mt * MT + wr + m * 16 + q * 4 + i;
          if (lr < row_cnt) {
            float v = acc[m][nn][i] + bc;
            v = v / (1.f + __expf(-v));
            hout[(size_t)(row_off + lr) * D_ + col] = (f16)v;
          }
        }
      }
    }
  }
}

// ---------------------------------------------------------------- gate ------
struct GP {
  const f16* h;
  const float* gW2[2]; const float* gb2[2]; const float* temp[2];
  const int* dom;
  float* gates;
};

__global__ __launch_bounds__(256) void gate_kernel(GP p) {
  int wid = (blockIdx.x * 256 + threadIdx.x) >> 6;
  int lane = threadIdx.x & 63;
  int z = wid >> 11;
  int pos = wid & (B_ - 1);
  int n = p.dom[pos];
  const f16* gh = p.h + ((size_t)(z * 11 + 10) * B_ + pos) * D_;
  const float* W = p.gW2[z] + (size_t)n * D_ * NTOT;
  float part[NTOT];
#pragma unroll
  for (int e = 0; e < NTOT; e++) part[e] = 0.f;
  for (int k = lane; k < D_; k += 64) {
    float a = (float)gh[k];
    const float* wrow = W + (size_t)k * NTOT;
#pragma unroll
    for (int e = 0; e < NTOT; e++) part[e] = fmaf(a, wrow[e], part[e]);
  }
#pragma unroll
  for (int e = 0; e < NTOT; e++) {
    float v = part[e];
#pragma unroll
    for (int s = 32; s > 0; s >>= 1) v += __shfl_xor(v, s, 64);
    part[e] = v;
  }
  float tv = p.temp[z][n];
  float tq = (tv > 15.f ? tv : log1pf(__expf(tv))) + 1e-4f;
  const float* b2 = p.gb2[z] + n * NTOT;
  float mx = -1e30f;
#pragma unroll
  for (int e = 0; e < NTOT; e++) { part[e] = (part[e] + b2[e]) / tq; mx = fmaxf(mx, part[e]); }
  float s = 0.f;
#pragma unroll
  for (int e = 0; e < NTOT; e++) { part[e] = __expf(part[e] - mx); s += part[e]; }
  float inv = 1.f / s;
  if (lane < NTOT) p.gates[((size_t)z * B_ + pos) * NTOT + lane] = part[lane] * inv;
}

// ---------------------------------------------------------------- layer 2 ---
struct L2P {
  const f16* h;
  const float* W2[2]; const float* sW2[2];
  const float* b2[2]; const float* sb2[2];
  const float* gates;
  const int* off; const int* cnt;
  f16* outp;   // [10][B_][768]
};

#define NBL2 2160
#define QX2  270

__global__ __launch_bounds__(256, 4) void layer2_kernel(L2P p) {
  const int raw = blockIdx.x;
  const int L = (raw & 7) * QX2 + (raw >> 3);
  const int zz = L / 216;
  const int rem = L % 216;
  const int n = rem / 24;
  const int x = rem % 24;
  const int z = zz / 5, es = zz % 5, ebase = es * 2;
  const int nt = x % 6, mt0 = x / 6;
  const int row_off = p.off[n], row_cnt = p.cnt[n];
  if (mt0 * MT >= row_cnt) return;

  __shared__ f16 As[2][MT][KT];
  __shared__ f16 Bs[2][MT][LDB];
  __shared__ float sg[MT][2];

  const int t = threadIdx.x;
  const int wave = t >> 6, lane = t & 63;
  const int wr = (wave >> 1) * 64, wc = (wave & 1) * 64;
  const int r0 = lane & 15, q = lane >> 4;
  const int lrow = lane >> 2;
  const int lk = 8 * ((lane & 3) ^ ((lane >> 3) & 3));
  const int qa = (q ^ ((r0 >> 1) & 3)) * 8;
  const int jbase = nt * MT;
  const int j4 = t >> 3, kq = (t & 7) * 4;

  const float* pb[2]; const float* wcol[2]; size_t slotOff[2];
  {
    int e0 = ebase, e1 = ebase + 1;
    const float* WB0 = (e0 < 6) ? (p.W2[z] + (size_t)(n*6+e0)*E2) : (p.sW2[z] + (size_t)(e0-6)*E2);
    const float* WB1 = (e1 < 6) ? (p.W2[z] + (size_t)(n*6+e1)*E2) : (p.sW2[z] + (size_t)(e1-6)*E2);
    wcol[0] = WB0 + jbase + j4 * 4;
    wcol[1] = WB1 + jbase + j4 * 4;
    pb[0] = (e0 < 6) ? (p.b2[z] + (size_t)(n*6+e0)*D_) : (p.sb2[z] + (size_t)(e0-6)*D_);
    pb[1] = (e1 < 6) ? (p.b2[z] + (size_t)(n*6+e1)*D_) : (p.sb2[z] + (size_t)(e1-6)*D_);
    slotOff[0] = (size_t)(z*11 + e0) * B_ * D_;
    slotOff[1] = (size_t)(z*11 + e1) * B_ * D_;
  }

  for (int mt = mt0; mt * MT < row_cnt; mt += 4) {
    for (int i = t; i < MT * 2; i += 256) {
      int rr = i >> 1, e = i & 1;
      int gp = row_off + mt * MT + rr;
      sg[rr][e] = (gp < B_ && (mt * MT + rr) < row_cnt)
                  ? p.gates[((size_t)z * B_ + gp) * NTOT + ebase + e] : 0.f;
    }
    __syncthreads();

    const f16* aB0[2]; const f16* aB1[2];
#pragma unroll
    for (int i = 0; i < 2; i++) {
      int rl = mt * MT + 32 * wave + 16 * i + lrow;
      int rr = (rl < row_cnt) ? (row_off + rl) : row_off;
      size_t rp = (size_t)rr * D_ + lk;
      aB0[i] = p.h + slotOff[0] + rp;
      aB1[i] = p.h + slotOff[1] + rp;
    }
    f16 gA[4], gB[4];
#pragma unroll
    for (int m = 0; m < 4; m++) {
      gA[m] = (f16)sg[wr + m * 16 + r0][0];
      gB[m] = (f16)sg[wr + m * 16 + r0][1];
    }

    f32x4 wv[4];
    auto LOADW = [&](int it) {
      const int ei = (it >= KI1);
      const int kb = (it - (ei ? KI1 : 0)) * KT + kq;
      const float* wb = wcol[ei];
#pragma unroll
      for (int r = 0; r < 4; r++) wv[r] = *(const f32x4*)(wb + (size_t)(kb + r) * D_);
    };
    auto GLOADA = [&](int buf, int it) {
      const int ei = (it >= KI1);
      const int k0 = (it - (ei ? KI1 : 0)) * KT;
      gload16((ei ? aB1[0] : aB0[0]) + k0, &As[buf][32 * wave][0]);
      gload16((ei ? aB1[1] : aB0[1]) + k0, &As[buf][32 * wave + 16][0]);
    };
    auto CVTW = [&](int buf) {
#pragma unroll
      for (int c = 0; c < 4; c++) {
        union { f16x4 v; f16x2 pp[2]; } u;
        u.pp[0] = pkrtz(wv[0][c], wv[1][c]);
        u.pp[1] = pkrtz(wv[2][c], wv[3][c]);
        *(f16x4*)&Bs[buf][j4 * 4 + c][kq] = u.v;
      }
    };

    f32x4 acc[4][4];
#pragma unroll
    for (int a = 0; a < 4; a++)
#pragma unroll
      for (int b = 0; b < 4; b++) acc[a][b] = (f32x4){0.f, 0.f, 0.f, 0.f};

    const int total = 2 * KI1;
    LOADW(0);
    GLOADA(0, 0);
    CVTW(0);
    __syncthreads();

    for (int it = 0; it < total; it++) {
      const int cur = it & 1;
      if (it + 1 < total) { LOADW(it + 1); GLOADA(cur ^ 1, it + 1); }
      SCHED0();
      const int ei = (it >= KI1);
      f16x8 af[4], bf[4];
#pragma unroll
      for (int m = 0; m < 4; m++) {
        af[m] = *(const f16x8*)&As[cur][wr + m * 16 + r0][qa];
        af[m] = af[m] * (ei ? gB[m] : gA[m]);
      }
#pragma unroll
      for (int nn = 0; nn < 4; nn++) bf[nn] = *(const f16x8*)&Bs[cur][wc + nn * 16 + r0][q * 8];
#pragma unroll
      for (int m = 0; m < 4; m++)
#pragma unroll
        for (int nn = 0; nn < 4; nn++)
          acc[m][nn] = __builtin_amdgcn_mfma_f32_16x16x32_f16(af[m], bf[nn], acc[m][nn], 0, 0, 0);
      SCHED0();
      if (it + 1 < total) CVTW(cur ^ 1);
      __syncthreads();
    }

#pragma unroll
    for (int nn = 0; nn < 4; nn++) {
      const int col = jbase + wc + nn * 16 + r0;
      float pbc0 = pb[0][col], pbc1 = pb[1][col];
#pragma unroll
      for (int m = 0; m < 4; m++) {
#pragma unroll
        for (int i = 0; i < 4; i++) {
          const int lrt = wr + m * 16 + q * 4 + i;
          if (mt * MT + lrt < row_cnt) {
            float v = acc[m][nn][i];
            v = fmaf(sg[lrt][0], pbc0, v);
            v = fmaf(sg[lrt][1], pbc1, v);
            p.outp[((size_t)zz * B_ + row_off + mt * MT + lrt) * D_ + col] = (f16)v;
          }
        }
      }
    }
    __syncthreads();
  }
}

// ---------------------------------------------------------------- reduce ----
__global__ __launch_bounds__(256) void reduce_kernel(const f16* outp, const int* perm,
                                                     float* out) {
  int idx = blockIdx.x * 256 + threadIdx.x;   // 2 * B_ * 96 total
  int z = idx / (B_ * 96);
  int rem = idx % (B_ * 96);
  int r = rem / 96, c8 = rem % 96;
  float s[8];
#pragma unroll
  for (int j = 0; j < 8; j++) s[j] = 0.f;
#pragma unroll
  for (int es = 0; es < 5; es++) {
    f16x8 v = *(const f16x8*)(outp + (((size_t)(z * 5 + es)) * B_ + r) * D_ + c8 * 8);
#pragma unroll
    for (int j = 0; j < 8; j++) s[j] += (float)v[j];
  }
  float* dst = out + (size_t)perm[r] * (2 * D_) + z * D_ + c8 * 8;
  *(f32x4*)dst = (f32x4){s[0], s[1], s[2], s[3]};
  *(f32x4*)(dst + 4) = (f32x4){s[4], s[5], s[6], s[7]};
}

// ---------------------------------------------------------------- launch ----
extern "C" void kernel_launch(void* const* d_in, const int* in_sizes, int n_in,
                              void* d_out, int out_size, void* d_ws, size_t ws_size,
                              hipStream_t stream) {
  const float* content = (const float*)d_in[0];
  const float* ftr     = (const float*)d_in[1];
  const int*   cat     = (const int*)d_in[2];
  const float* demb    = (const float*)d_in[3];

  const float* cW1  = (const float*)d_in[4];
  const float* cb1  = (const float*)d_in[5];
  const float* cW2  = (const float*)d_in[6];
  const float* cb2  = (const float*)d_in[7];
  const float* csW1 = (const float*)d_in[8];
  const float* csb1 = (const float*)d_in[9];
  const float* csW2 = (const float*)d_in[10];
  const float* csb2 = (const float*)d_in[11];
  const float* cgW1 = (const float*)d_in[12];
  const float* cgb1 = (const float*)d_in[13];
  const float* cgW2 = (const float*)d_in[14];
  const float* cgb2 = (const float*)d_in[15];
  const float* ctemp= (const float*)d_in[16];

  const float* fW1  = (const float*)d_in[17];
  const float* fb1  = (const float*)d_in[18];
  const float* fW2  = (const float*)d_in[19];
  const float* fb2  = (const float*)d_in[20];
  const float* fsW1 = (const float*)d_in[21];
  const float* fsb1 = (const float*)d_in[22];
  const float* fsW2 = (const float*)d_in[23];
  const float* fsb2 = (const float*)d_in[24];
  const float* fgW1 = (const float*)d_in[25];
  const float* fgb1 = (const float*)d_in[26];
  const float* fgW2 = (const float*)d_in[27];
  const float* fgb2 = (const float*)d_in[28];
  const float* ftemp= (const float*)d_in[29];

  char* wsb = (char*)d_ws;
  int* perm    = (int*)wsb;                        // 8 KB
  int* off     = (int*)(wsb + 8192);
  int* cnt     = (int*)(wsb + 8256);
  int* dom     = (int*)(wsb + 8320);               // 8 KB
  float* gates = (float*)(wsb + 16512);            // 160 KB
  float* dg    = (float*)(wsb + 180352);           // 55 KB
  f16* h       = (f16*)(wsb + 409600);             // 66 MB
  f16* x16a    = (f16*)(wsb + 69615616);           // 3 MB
  f16* x16b    = (f16*)(wsb + 72761344);           // 3 MB
  f16* outp    = (f16*)(wsb + 75907072);           // 30 MB
  float* out   = (float*)d_out;

  bucket_kernel<<<1, 256, 0, stream>>>(cat, perm, off, cnt, dom);

  cvt_perm_kernel<<<768, 256, 0, stream>>>(content, x16a, perm, (B_ * D_) / 8);
  cvt_perm_kernel<<<768, 256, 0, stream>>>(ftr, x16b, perm, (B_ * D_) / 8);

  DGP pd;
  pd.demb = demb; pd.gW1[0] = cgW1; pd.gW1[1] = fgW1;
  pd.gb1[0] = cgb1; pd.gb1[1] = fgb1; pd.dg = dg;
  dgate_kernel<<<dim3(3, 9, 2), 256, 0, stream>>>(pd);

  L1P p1;
  p1.x16p[0] = x16a; p1.x16p[1] = x16b;
  p1.W1[0] = cW1;  p1.W1[1] = fW1;
  p1.sW1[0] = csW1; p1.sW1[1] = fsW1;
  p1.gW1[0] = cgW1; p1.gW1[1] = fgW1;
  p1.b1[0] = cb1;  p1.b1[1] = fb1;
  p1.sb1[0] = csb1; p1.sb1[1] = fsb1;
  p1.dg = dg;
  p1.off = off; p1.cnt = cnt; p1.h = h;
  layer1_kernel<<<dim3(NBL1), 256, 0, stream>>>(p1);

  GP pg;
  pg.h = h; pg.gW2[0] = cgW2; pg.gW2[1] = fgW2;
  pg.gb2[0] = cgb2; pg.gb2[1] = fgb2;
  pg.temp[0] = ctemp; pg.temp[1] = ftemp;
  pg.dom = dom; pg.gates = gates;
  gate_kernel<<<dim3((2 * B_) / 4), 256, 0, stream>>>(pg);

  L2P p2;
  p2.h = h;
  p2.W2[0] = cW2;  p2.W2[1] = fW2;
  p2.sW2[0] = csW2; p2.sW2[1] = fsW2;
  p2.b2[0] = cb2;  p2.b2[1] = fb2;
  p2.sb2[0] = csb2; p2.sb2[1] = fsb2;
  p2.gates = gates; p2.off = off; p2.cnt = cnt; p2.outp = outp;
  layer2_kernel<<<dim3(NBL2), 256, 0, stream>>>(p2);

  reduce_kernel<<<dim3((2 * B_ * 96) / 256), 256, 0, stream>>>(outp, perm, out);

  (void)in_sizes; (void)n_in; (void)ws_size; (void)out_size;
}